// Round 11
// baseline (357.880 us; speedup 1.0000x reference)
//
#include <hip/hip_runtime.h>
#include <hip/hip_bf16.h>
#include <cstdint>

typedef short bf16x8 __attribute__((ext_vector_type(8)));
typedef float f32x4 __attribute__((ext_vector_type(4)));
typedef unsigned short ushort_t;

__device__ __forceinline__ ushort_t f2bf(float f) {
    uint32_t u = __float_as_uint(f);
    u = (u + 0x7fffu + ((u >> 16) & 1u)) >> 16;
    return (ushort_t)u;
}

// packed f32x2 -> bf16x2 (RNE, same rounding as f2bf)
__device__ __forceinline__ uint32_t cvtpk_bf16(float lo, float hi) {
    uint32_t r;
    asm("v_cvt_pk_bf16_f32 %0, %1, %2" : "=v"(r) : "v"(lo), "v"(hi));
    return r;
}

// async global->LDS, 16B per lane; LDS dest = wave-uniform base + lane*16
__device__ __forceinline__ void gl2lds16(const void* g, void* l) {
    __builtin_amdgcn_global_load_lds((const __attribute__((address_space(1))) void*)(g),
                                     (__attribute__((address_space(3))) void*)(l), 16, 0, 0);
}

__device__ __forceinline__ void wait_vm0() {
    asm volatile("s_waitcnt vmcnt(0)" ::: "memory");
}

// ---------------- hidden fp32 -> bf16 ----------------
__global__ void cvt_hidden(const float* __restrict__ in, ushort_t* __restrict__ out, int n4) {
    int i = blockIdx.x * blockDim.x + threadIdx.x;
    for (; i < n4; i += gridDim.x * blockDim.x) {
        float4 v = ((const float4*)in)[i];
        ushort_t tmp[4] __attribute__((aligned(8)));
        tmp[0] = f2bf(v.x); tmp[1] = f2bf(v.y); tmp[2] = f2bf(v.z); tmp[3] = f2bf(v.w);
        ((uint2*)out)[i] = *(uint2*)tmp;
    }
}

// ---------------- W [k][n] fp32 -> Wt [n][k] bf16 (3 matrices) ----------------
__global__ void wt_transpose(const float* __restrict__ Wq, const float* __restrict__ Wk,
                             const float* __restrict__ Wv, ushort_t* __restrict__ out) {
    __shared__ float tile[64][68];
    const float* W = blockIdx.z == 0 ? Wq : (blockIdx.z == 1 ? Wk : Wv);
    int k0 = blockIdx.x * 64, n0 = blockIdx.y * 64;
    int t = threadIdx.x;
    for (int i = 0; i < 4; ++i) {
        int e = i * 1024 + t * 4;
        int r = e >> 6, c = e & 63;
        float4 v = *(const float4*)(W + (k0 + r) * 768 + n0 + c);
        *(float4*)(&tile[r][c]) = v;
    }
    __syncthreads();
    ushort_t* o = out + blockIdx.z * 768 * 768;
    for (int i = 0; i < 2; ++i) {
        int e = i * 2048 + t * 8;
        int rn = e >> 6, ck = e & 63;
        ushort_t tmp[8] __attribute__((aligned(16)));
        for (int j = 0; j < 8; ++j) tmp[j] = f2bf(tile[ck + j][rn]);
        *(int4*)(o + (n0 + rn) * 768 + k0 + ck) = *(int4*)tmp;
    }
}

// ---------------- QKV GEMM: [8192x768] x [768x768] -> per-head bf16 ----------------
// z==2 (V) writes directly in transposed [bh][d][s] layout (saves the v_transpose pass)
__launch_bounds__(256, 2)
__global__ void qkv_gemm(const ushort_t* __restrict__ A, const ushort_t* __restrict__ Wt,
                         const float* __restrict__ bq, const float* __restrict__ bk,
                         const float* __restrict__ bv,
                         ushort_t* __restrict__ q_out, ushort_t* __restrict__ k_out,
                         ushort_t* __restrict__ vt_out) {
    __shared__ char smem[32768];
    char* sA = smem;
    char* sB = smem + 16384;
    int z = blockIdx.z;
    const ushort_t* Wz = Wt + z * 589824;
    const float* bias = z == 0 ? bq : (z == 1 ? bk : bv);
    int m0 = blockIdx.x * 128, n0 = blockIdx.y * 128;
    int t = threadIdx.x, lane = t & 63, w = t >> 6;
    int wr = w >> 1, wc = w & 1;
    int lr = lane & 15, lg = lane >> 4;
    f32x4 acc[4][4] = {};
    for (int kt = 0; kt < 768; kt += 64) {
        for (int i = 0; i < 4; ++i) {
            int e = i * 2048 + t * 8;
            int r = e >> 6, c = e & 63;
            bf16x8 va = *(const bf16x8*)(A + (m0 + r) * 768 + kt + c);
            *(bf16x8*)(sA + ((r * 128 + c * 2) ^ ((r & 7) << 4))) = va;
            bf16x8 vb = *(const bf16x8*)(Wz + (n0 + r) * 768 + kt + c);
            *(bf16x8*)(sB + ((r * 128 + c * 2) ^ ((r & 7) << 4))) = vb;
        }
        __syncthreads();
        bf16x8 af[2][4], bfr[2][4];
#pragma unroll
        for (int kf = 0; kf < 2; ++kf)
#pragma unroll
            for (int mf = 0; mf < 4; ++mf) {
                int row = wr * 64 + mf * 16 + lr;
                af[kf][mf] = *(const bf16x8*)(sA + ((row * 128 + (kf * 32 + lg * 8) * 2) ^ ((row & 7) << 4)));
            }
#pragma unroll
        for (int kf = 0; kf < 2; ++kf)
#pragma unroll
            for (int nf = 0; nf < 4; ++nf) {
                int row = wc * 64 + nf * 16 + lr;
                bfr[kf][nf] = *(const bf16x8*)(sB + ((row * 128 + (kf * 32 + lg * 8) * 2) ^ ((row & 7) << 4)));
            }
#pragma unroll
        for (int kf = 0; kf < 2; ++kf)
#pragma unroll
            for (int mf = 0; mf < 4; ++mf)
#pragma unroll
                for (int nf = 0; nf < 4; ++nf)
                    acc[mf][nf] = __builtin_amdgcn_mfma_f32_16x16x32_bf16(af[kf][mf], bfr[kf][nf], acc[mf][nf], 0, 0, 0);
        __syncthreads();
    }
    if (z == 2) {
        // V: write transposed vt[bh][d][s]; thread's 4 rr values are s-consecutive -> 8B packed store
        for (int nf = 0; nf < 4; ++nf) {
            int n = n0 + wc * 64 + nf * 16 + lr;
            float bv_ = bias[n];
            int h = n >> 6, d = n & 63;
            for (int mf = 0; mf < 4; ++mf) {
                int m = m0 + wr * 64 + mf * 16 + lg * 4;
                int b = m >> 11, s = m & 2047;
                ushort_t tmp[4] __attribute__((aligned(8)));
                for (int rr = 0; rr < 4; ++rr) tmp[rr] = f2bf(acc[mf][nf][rr] + bv_);
                *(uint2*)(vt_out + ((size_t)(b * 12 + h) * 64 + d) * 2048 + s) = *(uint2*)tmp;
            }
        }
    } else {
        ushort_t* outp = z == 0 ? q_out : k_out;
        float scale = z == 0 ? 0.125f : 1.0f;
        for (int nf = 0; nf < 4; ++nf) {
            int n = n0 + wc * 64 + nf * 16 + lr;
            float bv_ = bias[n];
            int h = n >> 6, d = n & 63;
            for (int mf = 0; mf < 4; ++mf) {
                for (int rr = 0; rr < 4; ++rr) {
                    int m = m0 + wr * 64 + mf * 16 + lg * 4 + rr;
                    float val = (acc[mf][nf][rr] + bv_) * scale;
                    int b = m >> 11, s = m & 2047;
                    outp[((b * 12 + h) * 2048 + s) * 64 + d] = f2bf(val);
                }
            }
        }
    }
}

// ---------------- flash ctx: QBLK=128, async dbuf, swapped QK + packed P-writes ----------------
// Swapped mfma(K,Q) (r9/r10-validated): lane holds p[q = w*32+mf*16+lr][k = n16*16+lg*4+r].
// P repack: 2x v_cvt_pk_bf16_f32 + 1x 8B LDS write per (n16,mf); sP byte layout identical to
// previous rounds, so the PV fragment reads below are byte-for-byte the passing r4-r10 code.
__launch_bounds__(256, 3)
__global__ void attn_ctx(const ushort_t* __restrict__ qs, const ushort_t* __restrict__ ks,
                         const ushort_t* __restrict__ vt, const float* __restrict__ mask,
                         float* __restrict__ ctx, float* __restrict__ invl_g) {
    __shared__ char smem[49152];
    char* sK = smem;            // 2 x 8KB (also Q staging, 16KB)
    char* sV = smem + 16384;    // 2 x 8KB
    char* sP = smem + 32768;    // 4 waves x 4KB (2 mf x 2KB)
    int qt = blockIdx.x, bh = blockIdx.y;
    int b = bh / 12, h = bh % 12;
    int q0 = qt * 128;
    int t = threadIdx.x, lane = t & 63, w = t >> 6;
    int lr = lane & 15, lg = lane >> 4;
    const ushort_t* Qb = qs + bh * 131072;
    const ushort_t* Kb = ks + bh * 131072;
    const ushort_t* Vb = vt + bh * 131072;
    const float* mb = mask + b * 2048;

    int rsub = lane >> 3;                    // row-in-8 for this lane's 16B chunk
    int jsw  = ((lane & 7) ^ rsub) * 8;      // pre-swizzled source column (elements)

    // stage Q (128x64 = 16KB) into sK area, linear LDS + swizzled source
#pragma unroll
    for (int i = 0; i < 4; ++i) {
        int r = i * 32 + w * 8 + rsub;
        gl2lds16(Qb + (q0 + r) * 64 + jsw, sK + i * 4096 + w * 1024);
    }
    wait_vm0();
    __syncthreads();
    bf16x8 qa[2][2];
#pragma unroll
    for (int mf = 0; mf < 2; ++mf)
#pragma unroll
        for (int kf = 0; kf < 2; ++kf) {
            int row = w * 32 + mf * 16 + lr;
            qa[mf][kf] = *(const bf16x8*)(sK + ((row * 128 + (kf * 32 + lg * 8) * 2) ^ ((row & 7) << 4)));
        }
    __syncthreads();
    // stage K0/V0 into buffer 0
#pragma unroll
    for (int i = 0; i < 2; ++i) {
        int r = i * 32 + w * 8 + rsub;
        gl2lds16(Kb + r * 64 + jsw, sK + i * 4096 + w * 1024);
        gl2lds16(Vb + r * 2048 + jsw, sV + i * 4096 + w * 1024);
    }
    wait_vm0();
    __syncthreads();

    float lsum[2] = {0.f, 0.f};
    f32x4 oacc[2][4] = {};
    int cur = 0;
    for (int kt = 0; kt < 32; ++kt) {
        char* sKc = sK + cur * 8192;
        char* sVc = sV + cur * 8192;
        if (kt < 31) {
            char* sKn = sK + (cur ^ 1) * 8192;
            char* sVn = sV + (cur ^ 1) * 8192;
            int nt = kt + 1;
#pragma unroll
            for (int i = 0; i < 2; ++i) {
                int r = i * 32 + w * 8 + rsub;
                gl2lds16(Kb + (nt * 64 + r) * 64 + jsw, sKn + i * 4096 + w * 1024);
                gl2lds16(Vb + r * 2048 + nt * 64 + jsw, sVn + i * 4096 + w * 1024);
            }
        }
        // QK^T (swapped operands) + exp -> packed sP writes (wave-private)
#pragma unroll
        for (int n16 = 0; n16 < 4; ++n16) {
            int krow = n16 * 16 + lr;
            bf16x8 kb0 = *(const bf16x8*)(sKc + ((krow * 128 + (lg * 8) * 2) ^ ((krow & 7) << 4)));
            bf16x8 kb1 = *(const bf16x8*)(sKc + ((krow * 128 + (32 + lg * 8) * 2) ^ ((krow & 7) << 4)));
            float4 m4 = *(const float4*)(mb + kt * 64 + n16 * 16 + lg * 4);
            float ma0 = (1.0f - m4.x) * -10000.0f;
            float ma1 = (1.0f - m4.y) * -10000.0f;
            float ma2 = (1.0f - m4.z) * -10000.0f;
            float ma3 = (1.0f - m4.w) * -10000.0f;
#pragma unroll
            for (int mf = 0; mf < 2; ++mf) {
                f32x4 sacc = {};
                sacc = __builtin_amdgcn_mfma_f32_16x16x32_bf16(kb0, qa[mf][0], sacc, 0, 0, 0);  // swapped
                sacc = __builtin_amdgcn_mfma_f32_16x16x32_bf16(kb1, qa[mf][1], sacc, 0, 0, 0);  // swapped
                float p0 = __expf(sacc[0] + ma0);
                float p1 = __expf(sacc[1] + ma1);
                float p2 = __expf(sacc[2] + ma2);
                float p3 = __expf(sacc[3] + ma3);
                lsum[mf] += (p0 + p1) + (p2 + p3);
                uint2 uu;
                uu.x = cvtpk_bf16(p0, p1);
                uu.y = cvtpk_bf16(p2, p3);
                // row = lr (q-local), bytes n16*32+lg*8 (= k*2), same XOR scheme as the reads below
                *(uint2*)(sP + w * 4096 + mf * 2048 +
                          ((lr * 128 + n16 * 32 + lg * 8) ^ ((lr & 7) << 4))) = uu;
            }
        }
        // PV (byte-identical to r4-r10)
        __builtin_amdgcn_s_setprio(1);
#pragma unroll
        for (int mf = 0; mf < 2; ++mf)
#pragma unroll
            for (int kf = 0; kf < 2; ++kf) {
                bf16x8 pa = *(const bf16x8*)(sP + w * 4096 + mf * 2048 +
                                             ((lr * 128 + (kf * 32 + lg * 8) * 2) ^ ((lr & 7) << 4)));
#pragma unroll
                for (int dt = 0; dt < 4; ++dt) {
                    int vrow = dt * 16 + lr;
                    bf16x8 vb = *(const bf16x8*)(sVc + ((vrow * 128 + (kf * 32 + lg * 8) * 2) ^ ((vrow & 7) << 4)));
                    oacc[mf][dt] = __builtin_amdgcn_mfma_f32_16x16x32_bf16(pa, vb, oacc[mf][dt], 0, 0, 0);
                }
            }
        __builtin_amdgcn_s_setprio(0);
        wait_vm0();        // explicit drain of gl2lds before the barrier (race insurance)
        __syncthreads();
        cur ^= 1;
    }
    // row sums: lane holds partial for q = w*32+mf*16+lr over its lg-subset of k; reduce across lg
#pragma unroll
    for (int mf = 0; mf < 2; ++mf) {
        lsum[mf] += __shfl_xor(lsum[mf], 16);
        lsum[mf] += __shfl_xor(lsum[mf], 32);
    }
    float invq[2] = {1.0f / lsum[0], 1.0f / lsum[1]};
    if (lg == 0) {
#pragma unroll
        for (int mf = 0; mf < 2; ++mf)
            invl_g[bh * 2048 + q0 + w * 32 + mf * 16 + lr] = invq[mf];
    }
#pragma unroll
    for (int mf = 0; mf < 2; ++mf) {
        float inv4[4];
#pragma unroll
        for (int r = 0; r < 4; ++r) inv4[r] = __shfl(invq[mf], lg * 4 + r, 16);
#pragma unroll
        for (int dt = 0; dt < 4; ++dt)
#pragma unroll
            for (int r = 0; r < 4; ++r) {
                int qabs = q0 + w * 32 + mf * 16 + lg * 4 + r;
                ctx[(size_t)(b * 2048 + qabs) * 768 + h * 64 + dt * 16 + lr] = oacc[mf][dt][r] * inv4[r];
            }
    }
}

// ---------------- probs: swapped mfma(K,Q) + vectorized LDS bounce + 256B-coalesced stores ----------------
__launch_bounds__(256)
__global__ void attn_probs(const ushort_t* __restrict__ qs, const ushort_t* __restrict__ ks,
                           const float* __restrict__ mask, const float* __restrict__ invl_g,
                           float* __restrict__ probs) {
    __shared__ char smem[24576];
    char* sK = smem;
    char* sP32 = smem + 8192;   // 4 waves x 4KB (16 rows x 64 fp32, chunk-XOR swizzled)
    int qt = blockIdx.x, bh = blockIdx.y;
    int b = bh / 12;
    int q0 = qt * 64;
    int t = threadIdx.x, lane = t & 63, w = t >> 6;
    int lr = lane & 15, lg = lane >> 4;
    const ushort_t* Qb = qs + bh * 131072;
    const ushort_t* Kb = ks + bh * 131072;
    const float* mb = mask + b * 2048;
    float* prow = probs + (size_t)bh * 4194304;

    // stage Q (64x64) via sK, grab per-wave fragments (round-4 verbatim)
    for (int i = 0; i < 2; ++i) {
        int e = i * 2048 + t * 8;
        int r = e >> 6, c = e & 63;
        *(bf16x8*)(sK + ((r * 128 + c * 2) ^ ((r & 7) << 4))) = *(const bf16x8*)(Qb + (q0 + r) * 64 + c);
    }
    __syncthreads();
    bf16x8 qa[2];
#pragma unroll
    for (int kf = 0; kf < 2; ++kf) {
        int row = w * 16 + lr;
        qa[kf] = *(const bf16x8*)(sK + ((row * 128 + (kf * 32 + lg * 8) * 2) ^ ((row & 7) << 4)));
    }
    __syncthreads();

    // swapped layout: this lane's single q-row
    float invl_q = invl_g[bh * 2048 + q0 + w * 16 + lr];

    char* myP = sP32 + w * 4096;
    for (int kt = 0; kt < 32; ++kt) {
        // K staging: round-4 verbatim
        for (int i = 0; i < 2; ++i) {
            int e = i * 2048 + t * 8;
            int r = e >> 6, c = e & 63;
            *(bf16x8*)(sK + ((r * 128 + c * 2) ^ ((r & 7) << 4))) = *(const bf16x8*)(Kb + (kt * 64 + r) * 64 + c);
        }
        __syncthreads();
#pragma unroll
        for (int n16 = 0; n16 < 4; ++n16) {
            int krow = n16 * 16 + lr;
            bf16x8 kb0 = *(const bf16x8*)(sK + ((krow * 128 + (lg * 8) * 2) ^ ((krow & 7) << 4)));
            bf16x8 kb1 = *(const bf16x8*)(sK + ((krow * 128 + (32 + lg * 8) * 2) ^ ((krow & 7) << 4)));
            f32x4 sacc = {};
            sacc = __builtin_amdgcn_mfma_f32_16x16x32_bf16(kb0, qa[0], sacc, 0, 0, 0);  // swapped (r9-validated)
            sacc = __builtin_amdgcn_mfma_f32_16x16x32_bf16(kb1, qa[1], sacc, 0, 0, 0);  // swapped
            float4 m4 = *(const float4*)(mb + kt * 64 + n16 * 16 + lg * 4);
            f32x4 pv;
            pv[0] = __expf(sacc[0] + (1.0f - m4.x) * -10000.0f) * invl_q;
            pv[1] = __expf(sacc[1] + (1.0f - m4.y) * -10000.0f) * invl_q;
            pv[2] = __expf(sacc[2] + (1.0f - m4.z) * -10000.0f) * invl_q;
            pv[3] = __expf(sacc[3] + (1.0f - m4.w) * -10000.0f) * invl_q;
            // vector LDS write: row = lr (q-local), chunk c = n16*4+lg stored at c^lr
            *(f32x4*)(myP + lr * 256 + (((n16 * 4 + lg) ^ lr) << 4)) = pv;
        }
        // wave-private readback (no block barrier needed), 4 rows x 256B coalesced stores
#pragma unroll
        for (int step = 0; step < 4; ++step) {
            int srow = step * 4 + lg;                      // 0..15
            f32x4 pv = *(const f32x4*)(myP + srow * 256 + ((lr ^ srow) << 4));
            *(f32x4*)(prow + (size_t)(q0 + w * 16 + srow) * 2048 + kt * 64 + lr * 4) = pv;
        }
        __syncthreads();
    }
}

extern "C" void kernel_launch(void* const* d_in, const int* in_sizes, int n_in,
                              void* d_out, int out_size, void* d_ws, size_t ws_size,
                              hipStream_t stream) {
    const float* hidden = (const float*)d_in[0];
    const float* mask   = (const float*)d_in[1];
    const float* Wq     = (const float*)d_in[2];
    const float* bq     = (const float*)d_in[3];
    const float* Wk     = (const float*)d_in[4];
    const float* bk     = (const float*)d_in[5];
    const float* Wv     = (const float*)d_in[6];
    const float* bv     = (const float*)d_in[7];
    float* ctx   = (float*)d_out;
    float* probs = ctx + 6291456;

    char* ws = (char*)d_ws;
    ushort_t* hidB = (ushort_t*)(ws);                 // 12.58 MB
    ushort_t* WtB  = (ushort_t*)(ws + 12582912);      // 3.54 MB (reused by invl later)
    ushort_t* qsB  = (ushort_t*)(ws + 16121856);      // 12.58 MB
    ushort_t* ksB  = (ushort_t*)(ws + 28704768);      // 12.58 MB
    ushort_t* vtB  = (ushort_t*)(ws + 41287680);      // 12.58 MB (V written pre-transposed)
    float*    invl = (float*)(ws + 12582912);         // overlaps WtB (dead after gemm)

    hipLaunchKernelGGL(cvt_hidden, dim3(6144), dim3(256), 0, stream, hidden, hidB, 1572864);
    hipLaunchKernelGGL(wt_transpose, dim3(12, 12, 3), dim3(256), 0, stream, Wq, Wk, Wv, WtB);
    hipLaunchKernelGGL(qkv_gemm, dim3(64, 6, 3), dim3(256), 0, stream,
                       hidB, WtB, bq, bk, bv, qsB, ksB, vtB);
    hipLaunchKernelGGL(attn_ctx, dim3(16, 48), dim3(256), 0, stream, qsB, ksB, vtB, mask, ctx, invl);
    hipLaunchKernelGGL(attn_probs, dim3(32, 48), dim3(256), 0, stream, qsB, ksB, mask, invl, probs);
}

// Round 12
// 289.976 us; speedup vs baseline: 1.2342x; 1.2342x over previous
//
#include <hip/hip_runtime.h>
#include <hip/hip_bf16.h>
#include <cstdint>

typedef short bf16x8 __attribute__((ext_vector_type(8)));
typedef float f32x4 __attribute__((ext_vector_type(4)));
typedef unsigned short ushort_t;

__device__ __forceinline__ ushort_t f2bf(float f) {
    uint32_t u = __float_as_uint(f);
    u = (u + 0x7fffu + ((u >> 16) & 1u)) >> 16;
    return (ushort_t)u;
}

// async global->LDS, 16B per lane; LDS dest = wave-uniform base + lane*16
__device__ __forceinline__ void gl2lds16(const void* g, void* l) {
    __builtin_amdgcn_global_load_lds((const __attribute__((address_space(1))) void*)(g),
                                     (__attribute__((address_space(3))) void*)(l), 16, 0, 0);
}

__device__ __forceinline__ void wait_vm0() {
    asm volatile("s_waitcnt vmcnt(0)" ::: "memory");
}

// ---------------- hidden fp32 -> bf16 ----------------
__global__ void cvt_hidden(const float* __restrict__ in, ushort_t* __restrict__ out, int n4) {
    int i = blockIdx.x * blockDim.x + threadIdx.x;
    for (; i < n4; i += gridDim.x * blockDim.x) {
        float4 v = ((const float4*)in)[i];
        ushort_t tmp[4] __attribute__((aligned(8)));
        tmp[0] = f2bf(v.x); tmp[1] = f2bf(v.y); tmp[2] = f2bf(v.z); tmp[3] = f2bf(v.w);
        ((uint2*)out)[i] = *(uint2*)tmp;
    }
}

// ---------------- W [k][n] fp32 -> Wt [n][k] bf16 (3 matrices) ----------------
__global__ void wt_transpose(const float* __restrict__ Wq, const float* __restrict__ Wk,
                             const float* __restrict__ Wv, ushort_t* __restrict__ out) {
    __shared__ float tile[64][68];
    const float* W = blockIdx.z == 0 ? Wq : (blockIdx.z == 1 ? Wk : Wv);
    int k0 = blockIdx.x * 64, n0 = blockIdx.y * 64;
    int t = threadIdx.x;
    for (int i = 0; i < 4; ++i) {
        int e = i * 1024 + t * 4;
        int r = e >> 6, c = e & 63;
        float4 v = *(const float4*)(W + (k0 + r) * 768 + n0 + c);
        *(float4*)(&tile[r][c]) = v;
    }
    __syncthreads();
    ushort_t* o = out + blockIdx.z * 768 * 768;
    for (int i = 0; i < 2; ++i) {
        int e = i * 2048 + t * 8;
        int rn = e >> 6, ck = e & 63;
        ushort_t tmp[8] __attribute__((aligned(16)));
        for (int j = 0; j < 8; ++j) tmp[j] = f2bf(tile[ck + j][rn]);
        *(int4*)(o + (n0 + rn) * 768 + k0 + ck) = *(int4*)tmp;
    }
}

// ---------------- QKV GEMM: [8192x768] x [768x768] -> per-head bf16 ----------------
// z==2 (V) writes directly in transposed [bh][d][s] layout (saves the v_transpose pass)
__launch_bounds__(256, 2)
__global__ void qkv_gemm(const ushort_t* __restrict__ A, const ushort_t* __restrict__ Wt,
                         const float* __restrict__ bq, const float* __restrict__ bk,
                         const float* __restrict__ bv,
                         ushort_t* __restrict__ q_out, ushort_t* __restrict__ k_out,
                         ushort_t* __restrict__ vt_out) {
    __shared__ char smem[32768];
    char* sA = smem;
    char* sB = smem + 16384;
    int z = blockIdx.z;
    const ushort_t* Wz = Wt + z * 589824;
    const float* bias = z == 0 ? bq : (z == 1 ? bk : bv);
    int m0 = blockIdx.x * 128, n0 = blockIdx.y * 128;
    int t = threadIdx.x, lane = t & 63, w = t >> 6;
    int wr = w >> 1, wc = w & 1;
    int lr = lane & 15, lg = lane >> 4;
    f32x4 acc[4][4] = {};
    for (int kt = 0; kt < 768; kt += 64) {
        for (int i = 0; i < 4; ++i) {
            int e = i * 2048 + t * 8;
            int r = e >> 6, c = e & 63;
            bf16x8 va = *(const bf16x8*)(A + (m0 + r) * 768 + kt + c);
            *(bf16x8*)(sA + ((r * 128 + c * 2) ^ ((r & 7) << 4))) = va;
            bf16x8 vb = *(const bf16x8*)(Wz + (n0 + r) * 768 + kt + c);
            *(bf16x8*)(sB + ((r * 128 + c * 2) ^ ((r & 7) << 4))) = vb;
        }
        __syncthreads();
        bf16x8 af[2][4], bfr[2][4];
#pragma unroll
        for (int kf = 0; kf < 2; ++kf)
#pragma unroll
            for (int mf = 0; mf < 4; ++mf) {
                int row = wr * 64 + mf * 16 + lr;
                af[kf][mf] = *(const bf16x8*)(sA + ((row * 128 + (kf * 32 + lg * 8) * 2) ^ ((row & 7) << 4)));
            }
#pragma unroll
        for (int kf = 0; kf < 2; ++kf)
#pragma unroll
            for (int nf = 0; nf < 4; ++nf) {
                int row = wc * 64 + nf * 16 + lr;
                bfr[kf][nf] = *(const bf16x8*)(sB + ((row * 128 + (kf * 32 + lg * 8) * 2) ^ ((row & 7) << 4)));
            }
#pragma unroll
        for (int kf = 0; kf < 2; ++kf)
#pragma unroll
            for (int mf = 0; mf < 4; ++mf)
#pragma unroll
                for (int nf = 0; nf < 4; ++nf)
                    acc[mf][nf] = __builtin_amdgcn_mfma_f32_16x16x32_bf16(af[kf][mf], bfr[kf][nf], acc[mf][nf], 0, 0, 0);
        __syncthreads();
    }
    if (z == 2) {
        // V: write transposed vt[bh][d][s]; thread's 4 rr values are s-consecutive -> 8B packed store
        for (int nf = 0; nf < 4; ++nf) {
            int n = n0 + wc * 64 + nf * 16 + lr;
            float bv_ = bias[n];
            int h = n >> 6, d = n & 63;
            for (int mf = 0; mf < 4; ++mf) {
                int m = m0 + wr * 64 + mf * 16 + lg * 4;
                int b = m >> 11, s = m & 2047;
                ushort_t tmp[4] __attribute__((aligned(8)));
                for (int rr = 0; rr < 4; ++rr) tmp[rr] = f2bf(acc[mf][nf][rr] + bv_);
                *(uint2*)(vt_out + ((size_t)(b * 12 + h) * 64 + d) * 2048 + s) = *(uint2*)tmp;
            }
        }
    } else {
        ushort_t* outp = z == 0 ? q_out : k_out;
        float scale = z == 0 ? 0.125f : 1.0f;
        for (int nf = 0; nf < 4; ++nf) {
            int n = n0 + wc * 64 + nf * 16 + lr;
            float bv_ = bias[n];
            int h = n >> 6, d = n & 63;
            for (int mf = 0; mf < 4; ++mf) {
                for (int rr = 0; rr < 4; ++rr) {
                    int m = m0 + wr * 64 + mf * 16 + lg * 4 + rr;
                    float val = (acc[mf][nf][rr] + bv_) * scale;
                    int b = m >> 11, s = m & 2047;
                    outp[((b * 12 + h) * 2048 + s) * 64 + d] = f2bf(val);
                }
            }
        }
    }
}

// ---------------- fused attention: pass1 = flash ctx (r10 verbatim), pass2 = probs ----------------
__launch_bounds__(256, 3)
__global__ void attn_fused(const ushort_t* __restrict__ qs, const ushort_t* __restrict__ ks,
                           const ushort_t* __restrict__ vt, const float* __restrict__ mask,
                           float* __restrict__ ctx, float* __restrict__ probs) {
    __shared__ char smem[49152];
    char* sK = smem;            // 2 x 8KB K dbuf (also Q staging, 16KB); reused by pass 2
    char* sV = smem + 16384;    // pass1: 2 x 8KB V dbuf; pass2: P region (with sP)
    char* sP = smem + 32768;    // pass1: 4 waves x 4KB
    int qt = blockIdx.x, bh = blockIdx.y;
    int b = bh / 12, h = bh % 12;
    int q0 = qt * 128;
    int t = threadIdx.x, lane = t & 63, w = t >> 6;
    int lr = lane & 15, lg = lane >> 4;
    const ushort_t* Qb = qs + bh * 131072;
    const ushort_t* Kb = ks + bh * 131072;
    const ushort_t* Vb = vt + bh * 131072;
    const float* mb = mask + b * 2048;

    int rsub = lane >> 3;                    // row-in-8 for this lane's 16B chunk
    int jsw  = ((lane & 7) ^ rsub) * 8;      // pre-swizzled source column (elements)

    // ---- pass 1 (byte-identical to the r10 343.8us ctx) ----
#pragma unroll
    for (int i = 0; i < 4; ++i) {
        int r = i * 32 + w * 8 + rsub;
        gl2lds16(Qb + (q0 + r) * 64 + jsw, sK + i * 4096 + w * 1024);
    }
    wait_vm0();
    __syncthreads();
    bf16x8 qa[2][2];
#pragma unroll
    for (int mf = 0; mf < 2; ++mf)
#pragma unroll
        for (int kf = 0; kf < 2; ++kf) {
            int row = w * 32 + mf * 16 + lr;
            qa[mf][kf] = *(const bf16x8*)(sK + ((row * 128 + (kf * 32 + lg * 8) * 2) ^ ((row & 7) << 4)));
        }
    __syncthreads();
#pragma unroll
    for (int i = 0; i < 2; ++i) {
        int r = i * 32 + w * 8 + rsub;
        gl2lds16(Kb + r * 64 + jsw, sK + i * 4096 + w * 1024);
        gl2lds16(Vb + r * 2048 + jsw, sV + i * 4096 + w * 1024);
    }
    wait_vm0();
    __syncthreads();

    float lsum[2][4] = {};
    f32x4 oacc[2][4] = {};
    int cur = 0;
    for (int kt = 0; kt < 32; ++kt) {
        char* sKc = sK + cur * 8192;
        char* sVc = sV + cur * 8192;
        if (kt < 31) {
            char* sKn = sK + (cur ^ 1) * 8192;
            char* sVn = sV + (cur ^ 1) * 8192;
            int nt = kt + 1;
#pragma unroll
            for (int i = 0; i < 2; ++i) {
                int r = i * 32 + w * 8 + rsub;
                gl2lds16(Kb + (nt * 64 + r) * 64 + jsw, sKn + i * 4096 + w * 1024);
                gl2lds16(Vb + r * 2048 + nt * 64 + jsw, sVn + i * 4096 + w * 1024);
            }
        }
#pragma unroll
        for (int n16 = 0; n16 < 4; ++n16) {
            int krow = n16 * 16 + lr;
            bf16x8 kb0 = *(const bf16x8*)(sKc + ((krow * 128 + (lg * 8) * 2) ^ ((krow & 7) << 4)));
            bf16x8 kb1 = *(const bf16x8*)(sKc + ((krow * 128 + (32 + lg * 8) * 2) ^ ((krow & 7) << 4)));
            float madd = (1.0f - mb[kt * 64 + krow]) * -10000.0f;
#pragma unroll
            for (int mf = 0; mf < 2; ++mf) {
                f32x4 sacc = {};
                sacc = __builtin_amdgcn_mfma_f32_16x16x32_bf16(qa[mf][0], kb0, sacc, 0, 0, 0);
                sacc = __builtin_amdgcn_mfma_f32_16x16x32_bf16(qa[mf][1], kb1, sacc, 0, 0, 0);
#pragma unroll
                for (int r = 0; r < 4; ++r) {
                    float p = __expf(sacc[r] + madd);   // unnormalized
                    lsum[mf][r] += p;
                    int qrow = lg * 4 + r;
                    *(ushort_t*)(sP + w * 4096 + mf * 2048 +
                                 ((qrow * 128 + krow * 2) ^ ((qrow & 7) << 4))) = f2bf(p);
                }
            }
        }
        __builtin_amdgcn_s_setprio(1);
#pragma unroll
        for (int mf = 0; mf < 2; ++mf)
#pragma unroll
            for (int kf = 0; kf < 2; ++kf) {
                bf16x8 pa = *(const bf16x8*)(sP + w * 4096 + mf * 2048 +
                                             ((lr * 128 + (kf * 32 + lg * 8) * 2) ^ ((lr & 7) << 4)));
#pragma unroll
                for (int dt = 0; dt < 4; ++dt) {
                    int vrow = dt * 16 + lr;
                    bf16x8 vb = *(const bf16x8*)(sVc + ((vrow * 128 + (kf * 32 + lg * 8) * 2) ^ ((vrow & 7) << 4)));
                    oacc[mf][dt] = __builtin_amdgcn_mfma_f32_16x16x32_bf16(pa, vb, oacc[mf][dt], 0, 0, 0);
                }
            }
        __builtin_amdgcn_s_setprio(0);
        wait_vm0();
        __syncthreads();
        cur ^= 1;
    }
#pragma unroll
    for (int off = 1; off < 16; off <<= 1)
#pragma unroll
        for (int mf = 0; mf < 2; ++mf)
#pragma unroll
            for (int r = 0; r < 4; ++r) lsum[mf][r] += __shfl_xor(lsum[mf][r], off, 16);
#pragma unroll
    for (int mf = 0; mf < 2; ++mf) {
        float invl[4];
#pragma unroll
        for (int r = 0; r < 4; ++r) invl[r] = 1.0f / lsum[mf][r];
#pragma unroll
        for (int dt = 0; dt < 4; ++dt)
#pragma unroll
            for (int r = 0; r < 4; ++r) {
                int qabs = q0 + w * 32 + mf * 16 + lg * 4 + r;
                ctx[(size_t)(b * 2048 + qabs) * 768 + h * 64 + dt * 16 + lr] = oacc[mf][dt][r] * invl[r];
            }
    }

    // ---- per-lane inverse for pass 2: lane needs q = w*32 + mf*16 + lr ----
    // lsum[mf][r] (uniform within each 16-lane lg-group) holds row lg*4+r; row lr lives in
    // group lg' = lr>>2, entry r' = lr&3. Broadcast 4, select explicitly (no runtime indexing).
    float inv2[2];
#pragma unroll
    for (int mf = 0; mf < 2; ++mf) {
        int srcl = (lr >> 2) << 4;
        float s0 = __shfl(lsum[mf][0], srcl, 64);
        float s1 = __shfl(lsum[mf][1], srcl, 64);
        float s2 = __shfl(lsum[mf][2], srcl, 64);
        float s3 = __shfl(lsum[mf][3], srcl, 64);
        float sa = (lr & 1) ? s1 : s0;
        float sb = (lr & 1) ? s3 : s2;
        inv2[mf] = 1.0f / ((lr & 2) ? sb : sa);
    }

    // ---- pass 2: probs (r10-probs loop at QBLK=128; swapped mfma(K,Q), f32x4 LDS bounce) ----
    float* prow = probs + (size_t)bh * 4194304;
    char* sP2 = smem + 16384 + w * 8192;   // per-wave 8KB (2 mf x 4KB)
#pragma unroll
    for (int i = 0; i < 2; ++i) {
        int r = i * 32 + w * 8 + rsub;
        gl2lds16(Kb + r * 64 + jsw, sK + i * 4096 + w * 1024);
    }
    wait_vm0();
    __syncthreads();
    cur = 0;
    for (int kt = 0; kt < 32; ++kt) {
        char* sKc = sK + cur * 8192;
        if (kt < 31) {
            char* sKn = sK + (cur ^ 1) * 8192;
#pragma unroll
            for (int i = 0; i < 2; ++i) {
                int r = i * 32 + w * 8 + rsub;
                gl2lds16(Kb + ((kt + 1) * 64 + r) * 64 + jsw, sKn + i * 4096 + w * 1024);
            }
        }
#pragma unroll
        for (int n16 = 0; n16 < 4; ++n16) {
            int krow = n16 * 16 + lr;
            bf16x8 kb0 = *(const bf16x8*)(sKc + ((krow * 128 + (lg * 8) * 2) ^ ((krow & 7) << 4)));
            bf16x8 kb1 = *(const bf16x8*)(sKc + ((krow * 128 + (32 + lg * 8) * 2) ^ ((krow & 7) << 4)));
            float4 m4 = *(const float4*)(mb + kt * 64 + n16 * 16 + lg * 4);
#pragma unroll
            for (int mf = 0; mf < 2; ++mf) {
                f32x4 sacc = {};
                sacc = __builtin_amdgcn_mfma_f32_16x16x32_bf16(kb0, qa[mf][0], sacc, 0, 0, 0);  // swapped
                sacc = __builtin_amdgcn_mfma_f32_16x16x32_bf16(kb1, qa[mf][1], sacc, 0, 0, 0);  // swapped
                f32x4 pv;
                pv[0] = __expf(sacc[0] + (1.0f - m4.x) * -10000.0f) * inv2[mf];
                pv[1] = __expf(sacc[1] + (1.0f - m4.y) * -10000.0f) * inv2[mf];
                pv[2] = __expf(sacc[2] + (1.0f - m4.z) * -10000.0f) * inv2[mf];
                pv[3] = __expf(sacc[3] + (1.0f - m4.w) * -10000.0f) * inv2[mf];
                *(f32x4*)(sP2 + mf * 4096 + lr * 256 + (((n16 * 4 + lg) ^ lr) << 4)) = pv;
            }
        }
        // wave-private readback, 4 rows x 256B coalesced stores per mf
#pragma unroll
        for (int mf = 0; mf < 2; ++mf)
#pragma unroll
            for (int step = 0; step < 4; ++step) {
                int srow = step * 4 + lg;
                f32x4 pv = *(const f32x4*)(sP2 + mf * 4096 + srow * 256 + ((lr ^ srow) << 4));
                *(f32x4*)(prow + (size_t)(q0 + w * 32 + mf * 16 + srow) * 2048 + kt * 64 + lr * 4) = pv;
            }
        wait_vm0();
        __syncthreads();
        cur ^= 1;
    }
}

extern "C" void kernel_launch(void* const* d_in, const int* in_sizes, int n_in,
                              void* d_out, int out_size, void* d_ws, size_t ws_size,
                              hipStream_t stream) {
    const float* hidden = (const float*)d_in[0];
    const float* mask   = (const float*)d_in[1];
    const float* Wq     = (const float*)d_in[2];
    const float* bq     = (const float*)d_in[3];
    const float* Wk     = (const float*)d_in[4];
    const float* bk     = (const float*)d_in[5];
    const float* Wv     = (const float*)d_in[6];
    const float* bv     = (const float*)d_in[7];
    float* ctx   = (float*)d_out;
    float* probs = ctx + 6291456;

    char* ws = (char*)d_ws;
    ushort_t* hidB = (ushort_t*)(ws);                 // 12.58 MB
    ushort_t* WtB  = (ushort_t*)(ws + 12582912);      // 3.54 MB
    ushort_t* qsB  = (ushort_t*)(ws + 16121856);      // 12.58 MB
    ushort_t* ksB  = (ushort_t*)(ws + 28704768);      // 12.58 MB
    ushort_t* vtB  = (ushort_t*)(ws + 41287680);      // 12.58 MB (V written pre-transposed)

    hipLaunchKernelGGL(cvt_hidden, dim3(6144), dim3(256), 0, stream, hidden, hidB, 1572864);
    hipLaunchKernelGGL(wt_transpose, dim3(12, 12, 3), dim3(256), 0, stream, Wq, Wk, Wv, WtB);
    hipLaunchKernelGGL(qkv_gemm, dim3(64, 6, 3), dim3(256), 0, stream,
                       hidB, WtB, bq, bk, bv, qsB, ksB, vtB);
    hipLaunchKernelGGL(attn_fused, dim3(16, 48), dim3(256), 0, stream, qsB, ksB, vtB, mask, ctx, probs);
}

// Round 13
// 281.425 us; speedup vs baseline: 1.2717x; 1.0304x over previous
//
#include <hip/hip_runtime.h>
#include <hip/hip_bf16.h>
#include <cstdint>

typedef short bf16x8 __attribute__((ext_vector_type(8)));
typedef float f32x4 __attribute__((ext_vector_type(4)));
typedef unsigned short ushort_t;

__device__ __forceinline__ ushort_t f2bf(float f) {
    uint32_t u = __float_as_uint(f);
    u = (u + 0x7fffu + ((u >> 16) & 1u)) >> 16;
    return (ushort_t)u;
}

// async global->LDS, 16B per lane; LDS dest = wave-uniform base + lane*16
__device__ __forceinline__ void gl2lds16(const void* g, void* l) {
    __builtin_amdgcn_global_load_lds((const __attribute__((address_space(1))) void*)(g),
                                     (__attribute__((address_space(3))) void*)(l), 16, 0, 0);
}

__device__ __forceinline__ void wait_vm0() {
    asm volatile("s_waitcnt vmcnt(0)" ::: "memory");
}
// leave the 8 newest vmem ops (probs stores) in flight; older gl2lds drain (FIFO)
__device__ __forceinline__ void wait_vm8() {
    asm volatile("s_waitcnt vmcnt(8)" ::: "memory");
}

// ---------------- hidden fp32 -> bf16 ----------------
__global__ void cvt_hidden(const float* __restrict__ in, ushort_t* __restrict__ out, int n4) {
    int i = blockIdx.x * blockDim.x + threadIdx.x;
    for (; i < n4; i += gridDim.x * blockDim.x) {
        float4 v = ((const float4*)in)[i];
        ushort_t tmp[4] __attribute__((aligned(8)));
        tmp[0] = f2bf(v.x); tmp[1] = f2bf(v.y); tmp[2] = f2bf(v.z); tmp[3] = f2bf(v.w);
        ((uint2*)out)[i] = *(uint2*)tmp;
    }
}

// ---------------- W [k][n] fp32 -> Wt [n][k] bf16 (3 matrices) ----------------
__global__ void wt_transpose(const float* __restrict__ Wq, const float* __restrict__ Wk,
                             const float* __restrict__ Wv, ushort_t* __restrict__ out) {
    __shared__ float tile[64][68];
    const float* W = blockIdx.z == 0 ? Wq : (blockIdx.z == 1 ? Wk : Wv);
    int k0 = blockIdx.x * 64, n0 = blockIdx.y * 64;
    int t = threadIdx.x;
    for (int i = 0; i < 4; ++i) {
        int e = i * 1024 + t * 4;
        int r = e >> 6, c = e & 63;
        float4 v = *(const float4*)(W + (k0 + r) * 768 + n0 + c);
        *(float4*)(&tile[r][c]) = v;
    }
    __syncthreads();
    ushort_t* o = out + blockIdx.z * 768 * 768;
    for (int i = 0; i < 2; ++i) {
        int e = i * 2048 + t * 8;
        int rn = e >> 6, ck = e & 63;
        ushort_t tmp[8] __attribute__((aligned(16)));
        for (int j = 0; j < 8; ++j) tmp[j] = f2bf(tile[ck + j][rn]);
        *(int4*)(o + (n0 + rn) * 768 + k0 + ck) = *(int4*)tmp;
    }
}

// ---------------- QKV GEMM: [8192x768] x [768x768] -> per-head bf16 ----------------
// z==2 (V) writes directly in transposed [bh][d][s] layout (saves the v_transpose pass)
__launch_bounds__(256, 2)
__global__ void qkv_gemm(const ushort_t* __restrict__ A, const ushort_t* __restrict__ Wt,
                         const float* __restrict__ bq, const float* __restrict__ bk,
                         const float* __restrict__ bv,
                         ushort_t* __restrict__ q_out, ushort_t* __restrict__ k_out,
                         ushort_t* __restrict__ vt_out) {
    __shared__ char smem[32768];
    char* sA = smem;
    char* sB = smem + 16384;
    int z = blockIdx.z;
    const ushort_t* Wz = Wt + z * 589824;
    const float* bias = z == 0 ? bq : (z == 1 ? bk : bv);
    int m0 = blockIdx.x * 128, n0 = blockIdx.y * 128;
    int t = threadIdx.x, lane = t & 63, w = t >> 6;
    int wr = w >> 1, wc = w & 1;
    int lr = lane & 15, lg = lane >> 4;
    f32x4 acc[4][4] = {};
    for (int kt = 0; kt < 768; kt += 64) {
        for (int i = 0; i < 4; ++i) {
            int e = i * 2048 + t * 8;
            int r = e >> 6, c = e & 63;
            bf16x8 va = *(const bf16x8*)(A + (m0 + r) * 768 + kt + c);
            *(bf16x8*)(sA + ((r * 128 + c * 2) ^ ((r & 7) << 4))) = va;
            bf16x8 vb = *(const bf16x8*)(Wz + (n0 + r) * 768 + kt + c);
            *(bf16x8*)(sB + ((r * 128 + c * 2) ^ ((r & 7) << 4))) = vb;
        }
        __syncthreads();
        bf16x8 af[2][4], bfr[2][4];
#pragma unroll
        for (int kf = 0; kf < 2; ++kf)
#pragma unroll
            for (int mf = 0; mf < 4; ++mf) {
                int row = wr * 64 + mf * 16 + lr;
                af[kf][mf] = *(const bf16x8*)(sA + ((row * 128 + (kf * 32 + lg * 8) * 2) ^ ((row & 7) << 4)));
            }
#pragma unroll
        for (int kf = 0; kf < 2; ++kf)
#pragma unroll
            for (int nf = 0; nf < 4; ++nf) {
                int row = wc * 64 + nf * 16 + lr;
                bfr[kf][nf] = *(const bf16x8*)(sB + ((row * 128 + (kf * 32 + lg * 8) * 2) ^ ((row & 7) << 4)));
            }
#pragma unroll
        for (int kf = 0; kf < 2; ++kf)
#pragma unroll
            for (int mf = 0; mf < 4; ++mf)
#pragma unroll
                for (int nf = 0; nf < 4; ++nf)
                    acc[mf][nf] = __builtin_amdgcn_mfma_f32_16x16x32_bf16(af[kf][mf], bfr[kf][nf], acc[mf][nf], 0, 0, 0);
        __syncthreads();
    }
    if (z == 2) {
        // V: write transposed vt[bh][d][s]; thread's 4 rr values are s-consecutive -> 8B packed store
        for (int nf = 0; nf < 4; ++nf) {
            int n = n0 + wc * 64 + nf * 16 + lr;
            float bv_ = bias[n];
            int h = n >> 6, d = n & 63;
            for (int mf = 0; mf < 4; ++mf) {
                int m = m0 + wr * 64 + mf * 16 + lg * 4;
                int b = m >> 11, s = m & 2047;
                ushort_t tmp[4] __attribute__((aligned(8)));
                for (int rr = 0; rr < 4; ++rr) tmp[rr] = f2bf(acc[mf][nf][rr] + bv_);
                *(uint2*)(vt_out + ((size_t)(b * 12 + h) * 64 + d) * 2048 + s) = *(uint2*)tmp;
            }
        }
    } else {
        ushort_t* outp = z == 0 ? q_out : k_out;
        float scale = z == 0 ? 0.125f : 1.0f;
        for (int nf = 0; nf < 4; ++nf) {
            int n = n0 + wc * 64 + nf * 16 + lr;
            float bv_ = bias[n];
            int h = n >> 6, d = n & 63;
            for (int mf = 0; mf < 4; ++mf) {
                for (int rr = 0; rr < 4; ++rr) {
                    int m = m0 + wr * 64 + mf * 16 + lg * 4 + rr;
                    float val = (acc[mf][nf][rr] + bv_) * scale;
                    int b = m >> 11, s = m & 2047;
                    outp[((b * 12 + h) * 2048 + s) * 64 + d] = f2bf(val);
                }
            }
        }
    }
}

// ---------------- fused attention: sweep0 = lsum only (light), sweepB = PV + probs (merged) ----------------
// Swapped mfma(K,Q) throughout (r9-r12 validated): lane holds p[q=w*32+mf*16+lr][k=n16*16+lg*4+r].
__launch_bounds__(256, 3)
__global__ void attn_fused(const ushort_t* __restrict__ qs, const ushort_t* __restrict__ ks,
                           const ushort_t* __restrict__ vt, const float* __restrict__ mask,
                           float* __restrict__ ctx, float* __restrict__ probs) {
    __shared__ char smem[49152];
    char* sK = smem;            // 2 x 8KB K dbuf (also Q staging, 16KB)
    char* sV = smem + 16384;    // 2 x 8KB V dbuf (sweepB)
    char* sP = smem + 32768;    // 4 waves x 4KB bf16 P (sweepB; PV source + probs source)
    int qt = blockIdx.x, bh = blockIdx.y;
    int b = bh / 12, h = bh % 12;
    int q0 = qt * 128;
    int t = threadIdx.x, lane = t & 63, w = t >> 6;
    int lr = lane & 15, lg = lane >> 4;
    const ushort_t* Qb = qs + bh * 131072;
    const ushort_t* Kb = ks + bh * 131072;
    const ushort_t* Vb = vt + bh * 131072;
    const float* mb = mask + b * 2048;
    float* prow = probs + (size_t)bh * 4194304;

    int rsub = lane >> 3;                    // row-in-8 for this lane's 16B chunk
    int jsw  = ((lane & 7) ^ rsub) * 8;      // pre-swizzled source column (elements)

    // stage Q (128x64 = 16KB) into sK area, linear LDS + swizzled source
#pragma unroll
    for (int i = 0; i < 4; ++i) {
        int r = i * 32 + w * 8 + rsub;
        gl2lds16(Qb + (q0 + r) * 64 + jsw, sK + i * 4096 + w * 1024);
    }
    wait_vm0();
    __syncthreads();
    bf16x8 qa[2][2];
#pragma unroll
    for (int mf = 0; mf < 2; ++mf)
#pragma unroll
        for (int kf = 0; kf < 2; ++kf) {
            int row = w * 32 + mf * 16 + lr;
            qa[mf][kf] = *(const bf16x8*)(sK + ((row * 128 + (kf * 32 + lg * 8) * 2) ^ ((row & 7) << 4)));
        }
    __syncthreads();

    // ==== sweep 0: QK^T + exp + row-sum only (no V, no PV, no stores) ====
#pragma unroll
    for (int i = 0; i < 2; ++i) {
        int r = i * 32 + w * 8 + rsub;
        gl2lds16(Kb + r * 64 + jsw, sK + i * 4096 + w * 1024);
    }
    wait_vm0();
    __syncthreads();
    float lsum[2] = {0.f, 0.f};
    int cur = 0;
    for (int kt = 0; kt < 32; ++kt) {
        char* sKc = sK + cur * 8192;
        if (kt < 31) {
            char* sKn = sK + (cur ^ 1) * 8192;
#pragma unroll
            for (int i = 0; i < 2; ++i) {
                int r = i * 32 + w * 8 + rsub;
                gl2lds16(Kb + ((kt + 1) * 64 + r) * 64 + jsw, sKn + i * 4096 + w * 1024);
            }
        }
#pragma unroll
        for (int n16 = 0; n16 < 4; ++n16) {
            int krow = n16 * 16 + lr;
            bf16x8 kb0 = *(const bf16x8*)(sKc + ((krow * 128 + (lg * 8) * 2) ^ ((krow & 7) << 4)));
            bf16x8 kb1 = *(const bf16x8*)(sKc + ((krow * 128 + (32 + lg * 8) * 2) ^ ((krow & 7) << 4)));
            float4 m4 = *(const float4*)(mb + kt * 64 + n16 * 16 + lg * 4);
            float ma0 = (1.0f - m4.x) * -10000.0f;
            float ma1 = (1.0f - m4.y) * -10000.0f;
            float ma2 = (1.0f - m4.z) * -10000.0f;
            float ma3 = (1.0f - m4.w) * -10000.0f;
#pragma unroll
            for (int mf = 0; mf < 2; ++mf) {
                f32x4 sacc = {};
                sacc = __builtin_amdgcn_mfma_f32_16x16x32_bf16(kb0, qa[mf][0], sacc, 0, 0, 0);  // swapped
                sacc = __builtin_amdgcn_mfma_f32_16x16x32_bf16(kb1, qa[mf][1], sacc, 0, 0, 0);  // swapped
                lsum[mf] += (__expf(sacc[0] + ma0) + __expf(sacc[1] + ma1))
                          + (__expf(sacc[2] + ma2) + __expf(sacc[3] + ma3));
            }
        }
        wait_vm0();
        __syncthreads();
        cur ^= 1;
    }
    // lane holds partial sum for q = w*32+mf*16+lr over its lg-subset; reduce across lg groups
#pragma unroll
    for (int mf = 0; mf < 2; ++mf) {
        lsum[mf] += __shfl_xor(lsum[mf], 16);
        lsum[mf] += __shfl_xor(lsum[mf], 32);
    }
    float inv2[2] = {1.0f / lsum[0], 1.0f / lsum[1]};

    // ==== sweep B: p (normalized) -> PV + probs, one pass ====
#pragma unroll
    for (int i = 0; i < 2; ++i) {
        int r = i * 32 + w * 8 + rsub;
        gl2lds16(Kb + r * 64 + jsw, sK + i * 4096 + w * 1024);
        gl2lds16(Vb + r * 2048 + jsw, sV + i * 4096 + w * 1024);
    }
    wait_vm0();
    __syncthreads();

    f32x4 oacc[2][4] = {};
    cur = 0;
    for (int kt = 0; kt < 32; ++kt) {
        char* sKc = sK + cur * 8192;
        char* sVc = sV + cur * 8192;
        if (kt < 31) {
            char* sKn = sK + (cur ^ 1) * 8192;
            char* sVn = sV + (cur ^ 1) * 8192;
            int nt = kt + 1;
#pragma unroll
            for (int i = 0; i < 2; ++i) {
                int r = i * 32 + w * 8 + rsub;
                gl2lds16(Kb + (nt * 64 + r) * 64 + jsw, sKn + i * 4096 + w * 1024);
                gl2lds16(Vb + r * 2048 + nt * 64 + jsw, sVn + i * 4096 + w * 1024);
            }
        }
        // QK^T (swapped) + exp*inv -> packed bf16 sP writes (r11-validated byte layout)
#pragma unroll
        for (int n16 = 0; n16 < 4; ++n16) {
            int krow = n16 * 16 + lr;
            bf16x8 kb0 = *(const bf16x8*)(sKc + ((krow * 128 + (lg * 8) * 2) ^ ((krow & 7) << 4)));
            bf16x8 kb1 = *(const bf16x8*)(sKc + ((krow * 128 + (32 + lg * 8) * 2) ^ ((krow & 7) << 4)));
            float4 m4 = *(const float4*)(mb + kt * 64 + n16 * 16 + lg * 4);
            float ma0 = (1.0f - m4.x) * -10000.0f;
            float ma1 = (1.0f - m4.y) * -10000.0f;
            float ma2 = (1.0f - m4.z) * -10000.0f;
            float ma3 = (1.0f - m4.w) * -10000.0f;
#pragma unroll
            for (int mf = 0; mf < 2; ++mf) {
                f32x4 sacc = {};
                sacc = __builtin_amdgcn_mfma_f32_16x16x32_bf16(kb0, qa[mf][0], sacc, 0, 0, 0);  // swapped
                sacc = __builtin_amdgcn_mfma_f32_16x16x32_bf16(kb1, qa[mf][1], sacc, 0, 0, 0);  // swapped
                ushort_t tmp[4] __attribute__((aligned(8)));
                tmp[0] = f2bf(__expf(sacc[0] + ma0) * inv2[mf]);
                tmp[1] = f2bf(__expf(sacc[1] + ma1) * inv2[mf]);
                tmp[2] = f2bf(__expf(sacc[2] + ma2) * inv2[mf]);
                tmp[3] = f2bf(__expf(sacc[3] + ma3) * inv2[mf]);
                *(uint2*)(sP + w * 4096 + mf * 2048 +
                          ((lr * 128 + n16 * 32 + lg * 8) ^ ((lr & 7) << 4))) = *(uint2*)tmp;
            }
        }
        // PV (byte-identical reads to r4-r12)
        __builtin_amdgcn_s_setprio(1);
#pragma unroll
        for (int mf = 0; mf < 2; ++mf)
#pragma unroll
            for (int kf = 0; kf < 2; ++kf) {
                bf16x8 pa = *(const bf16x8*)(sP + w * 4096 + mf * 2048 +
                                             ((lr * 128 + (kf * 32 + lg * 8) * 2) ^ ((lr & 7) << 4)));
#pragma unroll
                for (int dt = 0; dt < 4; ++dt) {
                    int vrow = dt * 16 + lr;
                    bf16x8 vb = *(const bf16x8*)(sVc + ((vrow * 128 + (kf * 32 + lg * 8) * 2) ^ ((vrow & 7) << 4)));
                    oacc[mf][dt] = __builtin_amdgcn_mfma_f32_16x16x32_bf16(pa, vb, oacc[mf][dt], 0, 0, 0);
                }
            }
        __builtin_amdgcn_s_setprio(0);
        // probs: read the same bf16 sP back (wave-private), expand to f32, 256B-coalesced stores
#pragma unroll
        for (int mf = 0; mf < 2; ++mf)
#pragma unroll
            for (int step = 0; step < 4; ++step) {
                int srow = step * 4 + lg;
                uint2 uu = *(const uint2*)(sP + w * 4096 + mf * 2048 +
                                           ((srow * 128 + lr * 8) ^ ((srow & 7) << 4)));
                f32x4 pv;
                pv[0] = __uint_as_float((uu.x & 0xffffu) << 16);
                pv[1] = __uint_as_float(uu.x & 0xffff0000u);
                pv[2] = __uint_as_float((uu.y & 0xffffu) << 16);
                pv[3] = __uint_as_float(uu.y & 0xffff0000u);
                *(f32x4*)(prow + (size_t)(q0 + w * 32 + mf * 16 + srow) * 2048 + kt * 64 + lr * 4) = pv;
            }
        wait_vm8();        // drain gl2lds (older); keep the 8 probs stores in flight
        __syncthreads();
        cur ^= 1;
    }
    // ctx epilogue: p was pre-normalized, so oacc is the final context
#pragma unroll
    for (int mf = 0; mf < 2; ++mf)
#pragma unroll
        for (int dt = 0; dt < 4; ++dt)
#pragma unroll
            for (int r = 0; r < 4; ++r) {
                int qabs = q0 + w * 32 + mf * 16 + lg * 4 + r;
                ctx[(size_t)(b * 2048 + qabs) * 768 + h * 64 + dt * 16 + lr] = oacc[mf][dt][r];
            }
}

extern "C" void kernel_launch(void* const* d_in, const int* in_sizes, int n_in,
                              void* d_out, int out_size, void* d_ws, size_t ws_size,
                              hipStream_t stream) {
    const float* hidden = (const float*)d_in[0];
    const float* mask   = (const float*)d_in[1];
    const float* Wq     = (const float*)d_in[2];
    const float* bq     = (const float*)d_in[3];
    const float* Wk     = (const float*)d_in[4];
    const float* bk     = (const float*)d_in[5];
    const float* Wv     = (const float*)d_in[6];
    const float* bv     = (const float*)d_in[7];
    float* ctx   = (float*)d_out;
    float* probs = ctx + 6291456;

    char* ws = (char*)d_ws;
    ushort_t* hidB = (ushort_t*)(ws);                 // 12.58 MB
    ushort_t* WtB  = (ushort_t*)(ws + 12582912);      // 3.54 MB
    ushort_t* qsB  = (ushort_t*)(ws + 16121856);      // 12.58 MB
    ushort_t* ksB  = (ushort_t*)(ws + 28704768);      // 12.58 MB
    ushort_t* vtB  = (ushort_t*)(ws + 41287680);      // 12.58 MB (V written pre-transposed)

    hipLaunchKernelGGL(cvt_hidden, dim3(6144), dim3(256), 0, stream, hidden, hidB, 1572864);
    hipLaunchKernelGGL(wt_transpose, dim3(12, 12, 3), dim3(256), 0, stream, Wq, Wk, Wv, WtB);
    hipLaunchKernelGGL(qkv_gemm, dim3(64, 6, 3), dim3(256), 0, stream,
                       hidB, WtB, bq, bk, bv, qsB, ksB, vtB);
    hipLaunchKernelGGL(attn_fused, dim3(16, 48), dim3(256), 0, stream, qsB, ksB, vtB, mask, ctx, probs);
}